// Round 4
// baseline (96.922 us; speedup 1.0000x reference)
//
#include <hip/hip_runtime.h>
#include <math.h>

#define KSIZE 11
#define PAD 5

struct GaussW { float w[KSIZE]; };

#define B_    4
#define D_    160
#define H_    192
#define W_    192
#define W4_   48            // W in float4 units
#define TW4   16            // tile width in float4 (64 floats)
#define TH    32            // tile rows (h)
#define DSEG  16            // D-segment per block
#define NH    (H_ / TH)     // 6
#define NWT   (W_ / (TW4*4))// 3
#define NDS   (D_ / DSEG)   // 10
#define NBLK  (B_ * NH * NWT * NDS)   // 720
#define NSTEP (DSEG + KSIZE - 1)      // 26

#define INROWS 42           // TH + 10 (h-halo)
#define INW4   20           // TW4 + 4 (w-halo)
#define IN_STR4 21          // LDS row stride, f4 (odd, 16B-aligned rows)
#define WT_STR4 17          // LDS row stride, f4
#define NSTAGE (INROWS * INW4)   // 840 staged float4 per plane
#define NWITEM (INROWS * TW4)    // 672 W-conv items per plane

__global__ __launch_bounds__(256, 3) void blur3d_fused2(const float4* __restrict__ src,
                                                        float4* __restrict__ dst,
                                                        GaussW g) {
    __shared__ __align__(16) float lds_in[INROWS * IN_STR4 * 4];  // 14112 B
    __shared__ __align__(16) float lds_wt[INROWS * WT_STR4 * 4];  // 11424 B

    // Chunked XCD swizzle, ds innermost so d-neighbor blocks (sharing halo
    // planes) are dispatch-adjacent on the same XCD.
    int bid = blockIdx.x;
    int L = (bid & 7) * (NBLK / 8) + (bid >> 3);
    int ds = L % NDS; L /= NDS;
    int wx = L % NWT; L /= NWT;
    int hy = L % NH;
    int b  = L / NH;

    const int h0  = hy * TH;
    const int w0q = wx * TW4;
    const int d0  = ds * DSEG;

    const int tid = threadIdx.x;
    const int tx4 = tid & 15;      // 16 consecutive lanes along w (f4)
    const int ty  = tid >> 4;      // 0..15, owns output rows 2ty, 2ty+1

    const int batchBase = b * (D_ * H_ * W4_);   // float4 index

    float4 ring0[KSIZE], ring1[KSIZE];
#pragma unroll
    for (int t = 0; t < KSIZE; ++t) {
        ring0[t] = make_float4(0.f, 0.f, 0.f, 0.f);
        ring1[t] = make_float4(0.f, 0.f, 0.f, 0.f);
    }

    float4 pf[4];
    auto issue_loads = [&](int din) {
#pragma unroll
        for (int j = 0; j < 4; ++j) {
            pf[j] = make_float4(0.f, 0.f, 0.f, 0.f);
            int it = tid + j * 256;
            if (it < NSTAGE && din >= 0 && din < D_) {
                int ir = it / INW4, jc = it % INW4;
                int h = h0 - PAD + ir;
                int q = w0q - 2 + jc;
                if (h >= 0 && h < H_ && q >= 0 && q < W4_)
                    pf[j] = src[batchBase + din * (H_ * W4_) + h * W4_ + q];
            }
        }
    };

    issue_loads(d0 - PAD);

    for (int k = 0; k < NSTEP; ++k) {
        const int din = d0 - PAD + k;

        __syncthreads();   // previous step's LDS reads complete
#pragma unroll
        for (int j = 0; j < 4; ++j) {
            int it = tid + j * 256;
            if (it < NSTAGE) {
                int ir = it / INW4, jc = it % INW4;
                *(float4*)&lds_in[(ir * IN_STR4 + jc) * 4] = pf[j];
            }
        }
        __syncthreads();

        // Prefetch next plane; completes under the conv phases (T14).
        issue_loads(din + 1);

        // ---- W-conv: 672 items (42 rows x 16 c4), 16-lane groups read
        //      16 consecutive f4 -> conflict-free. ----
#pragma unroll
        for (int j = 0; j < 3; ++j) {
            int it = tid + j * 256;
            if (it < NWITEM) {
                int r = it >> 4, c4 = it & 15;
                float win[20];
                const float* row = &lds_in[r * IN_STR4 * 4];
#pragma unroll
                for (int u = 0; u < 5; ++u) {
                    float4 v = *(const float4*)&row[(c4 + u) * 4];
                    win[4 * u + 0] = v.x; win[4 * u + 1] = v.y;
                    win[4 * u + 2] = v.z; win[4 * u + 3] = v.w;
                }
                float4 a = make_float4(0.f, 0.f, 0.f, 0.f);
#pragma unroll
                for (int t = 0; t < KSIZE; ++t) {
                    float wt = g.w[t];
                    a.x += wt * win[3 + t]; a.y += wt * win[4 + t];
                    a.z += wt * win[5 + t]; a.w += wt * win[6 + t];
                }
                *(float4*)&lds_wt[(r * WT_STR4 + c4) * 4] = a;
            }
        }
        __syncthreads();

        // ---- H-conv: rows 2ty, 2ty+1 share 12 reads (16-lane contiguous). ----
        float4 wh0 = make_float4(0.f, 0.f, 0.f, 0.f);
        float4 wh1 = make_float4(0.f, 0.f, 0.f, 0.f);
#pragma unroll
        for (int j = 0; j < KSIZE + 1; ++j) {
            float4 v = *(const float4*)&lds_wt[((2 * ty + j) * WT_STR4 + tx4) * 4];
            if (j < KSIZE) {
                float wt = g.w[j];
                wh0.x += wt * v.x; wh0.y += wt * v.y;
                wh0.z += wt * v.z; wh0.w += wt * v.w;
            }
            if (j > 0) {
                float wt = g.w[j - 1];
                wh1.x += wt * v.x; wh1.y += wt * v.y;
                wh1.z += wt * v.z; wh1.w += wt * v.w;
            }
        }

        // ---- ring shift (static indices) + push ----
#pragma unroll
        for (int t = 0; t < KSIZE - 1; ++t) { ring0[t] = ring0[t + 1]; ring1[t] = ring1[t + 1]; }
        ring0[KSIZE - 1] = wh0;
        ring1[KSIZE - 1] = wh1;

        // ---- D-conv + emit ----
        if (k >= KSIZE - 1) {
            const int dout = din - PAD;   // in [d0, d0+DSEG)
            float4 o0 = make_float4(0.f, 0.f, 0.f, 0.f);
            float4 o1 = make_float4(0.f, 0.f, 0.f, 0.f);
#pragma unroll
            for (int t = 0; t < KSIZE; ++t) {
                float wt = g.w[t];
                o0.x += wt * ring0[t].x; o0.y += wt * ring0[t].y;
                o0.z += wt * ring0[t].z; o0.w += wt * ring0[t].w;
                o1.x += wt * ring1[t].x; o1.y += wt * ring1[t].y;
                o1.z += wt * ring1[t].z; o1.w += wt * ring1[t].w;
            }
            float4* outp = dst + batchBase + dout * (H_ * W4_) + (h0 + 2 * ty) * W4_ + w0q + tx4;
            outp[0]   = o0;
            outp[W4_] = o1;
        }
    }
}

extern "C" void kernel_launch(void* const* d_in, const int* in_sizes, int n_in,
                              void* d_out, int out_size, void* d_ws, size_t ws_size,
                              hipStream_t stream) {
    const float* x = (const float*)d_in[0];
    float* out = (float*)d_out;
    (void)d_ws; (void)ws_size; (void)in_sizes; (void)n_in; (void)out_size;

    // Gaussian weights, sigma = 1.5, ksize = 11, normalized.
    GaussW g;
    {
        double tmp[KSIZE], s = 0.0;
        for (int i = 0; i < KSIZE; ++i) {
            double dd = (double)(i - PAD);
            tmp[i] = exp(-(dd * dd) / (2.0 * 1.5 * 1.5));
            s += tmp[i];
        }
        for (int i = 0; i < KSIZE; ++i) g.w[i] = (float)(tmp[i] / s);
    }

    blur3d_fused2<<<NBLK, 256, 0, stream>>>((const float4*)x, (float4*)out, g);
}

// Round 5
// 63.994 us; speedup vs baseline: 1.5145x; 1.5145x over previous
//
#include <hip/hip_runtime.h>
#include <hip/hip_bf16.h>
#include <math.h>

#define KSIZE 11
#define PAD 5

struct GaussW { float w[KSIZE]; };

#define B_    4
#define D_    160
#define H_    192
#define W_    192
#define W4_   48

// ---------------- Kernel A: per-plane fused W+H blur (f32 -> bf16) ---------
#define TW4    16              // tile width in float4 (64 floats)
#define TH     48              // tile height (rows)
#define DCH    10              // planes per block
#define NH     (H_ / TH)       // 4
#define NWT    (W_ / (TW4*4))  // 3
#define NDC    (D_ / DCH)      // 16
#define NBLK_A (B_ * NH * NWT * NDC)   // 768
#define INROWS (TH + 10)       // 58
#define INW4   (TW4 + 4)       // 20
#define IN_STR4 21             // odd stride -> rows rotate across bank groups
#define WT_STR4 17
#define NSTAGE (INROWS * INW4) // 1160
#define NWIT   (INROWS * 4)    // 232 W-conv items (4 f4 wide each)

static __device__ inline unsigned short f2bf(float f) {
    __hip_bfloat16 h = __float2bfloat16(f);
    return __builtin_bit_cast(unsigned short, h);
}

__global__ __launch_bounds__(256, 3) void blur_wh(const float4* __restrict__ src,
                                                  ushort4* __restrict__ wsb,
                                                  GaussW g) {
    __shared__ __align__(16) float lds_in[INROWS * IN_STR4 * 4];  // 19488 B
    __shared__ __align__(16) float lds_wt[INROWS * WT_STR4 * 4];  // 15776 B

    // XCD swizzle (768 % 8 == 0): w/h neighbors (sharing halo rows) adjacent.
    int bid = blockIdx.x;
    int L = (bid & 7) * (NBLK_A / 8) + (bid >> 3);
    int wx = L % NWT; L /= NWT;
    int hy = L % NH;  L /= NH;
    int dc = L % NDC;
    int b  = L / NDC;

    const int h0  = hy * TH;
    const int w0q = wx * TW4;
    const int d0  = dc * DCH;
    const int tid = threadIdx.x;

    float4 pf[5];
    auto issue = [&](int d) {
        const float4* plane = src + (b * D_ + d) * (H_ * W4_);
#pragma unroll
        for (int j = 0; j < 5; ++j) {
            pf[j] = make_float4(0.f, 0.f, 0.f, 0.f);
            int it = tid + j * 256;
            if (it < NSTAGE) {
                int ir = it / INW4, jc = it - ir * INW4;
                int h = h0 - PAD + ir;
                int q = w0q - 2 + jc;
                if (h >= 0 && h < H_ && q >= 0 && q < W4_)
                    pf[j] = plane[h * W4_ + q];
            }
        }
    };
    auto stage_write = [&]() {
#pragma unroll
        for (int j = 0; j < 5; ++j) {
            int it = tid + j * 256;
            if (it < NSTAGE) {
                int ir = it / INW4, jc = it - ir * INW4;
                *(float4*)&lds_in[(ir * IN_STR4 + jc) * 4] = pf[j];
            }
        }
    };

    issue(d0);
    stage_write();
    issue(d0 + 1);
    __syncthreads();

    for (int p = 0; p < DCH; ++p) {
        // ---- region 1: W-conv plane p: lds_in -> lds_wt ----
        if (tid < NWIT) {
            const int gq = tid & 3, r = tid >> 2;   // 4-f4-wide item
            float win[32];
            const float* row = &lds_in[(r * IN_STR4 + gq * 4) * 4];
#pragma unroll
            for (int u = 0; u < 8; ++u) {
                float4 v = *(const float4*)&row[u * 4];
                win[4*u+0] = v.x; win[4*u+1] = v.y;
                win[4*u+2] = v.z; win[4*u+3] = v.w;
            }
            float o[16];
#pragma unroll
            for (int i = 0; i < 16; ++i) {
                float a = 0.f;
#pragma unroll
                for (int t = 0; t < KSIZE; ++t) a += g.w[t] * win[i + 3 + t];
                o[i] = a;
            }
            float* wrow = &lds_wt[(r * WT_STR4 + gq * 4) * 4];
#pragma unroll
            for (int c = 0; c < 4; ++c)
                *(float4*)&wrow[c * 4] =
                    make_float4(o[4*c], o[4*c+1], o[4*c+2], o[4*c+3]);
        }
        __syncthreads();   // wt ready; lds_in fully consumed

        // ---- region 2: stage plane p+1 into lds_in (overlaps H-conv),
        //      issue plane p+2, H-conv plane p from lds_wt -> bf16 store ----
        if (p + 1 < DCH) stage_write();
        if (p + 2 < DCH) issue(d0 + p + 2);

        {
            const int c4 = tid & 15, grp = tid >> 4;  // rows 3grp..3grp+2
            float4 a0 = make_float4(0.f,0.f,0.f,0.f);
            float4 a1 = a0, a2 = a0;
#pragma unroll
            for (int j = 0; j < 13; ++j) {
                float4 v = *(const float4*)&lds_wt[((3*grp + j) * WT_STR4 + c4) * 4];
                if (j <= 10) {
                    float wt = g.w[j];
                    a0.x += wt*v.x; a0.y += wt*v.y; a0.z += wt*v.z; a0.w += wt*v.w;
                }
                if (j >= 1 && j <= 11) {
                    float wt = g.w[j-1];
                    a1.x += wt*v.x; a1.y += wt*v.y; a1.z += wt*v.z; a1.w += wt*v.w;
                }
                if (j >= 2) {
                    float wt = g.w[j-2];
                    a2.x += wt*v.x; a2.y += wt*v.y; a2.z += wt*v.z; a2.w += wt*v.w;
                }
            }
            const int d = d0 + p;
            ushort4* wp = wsb + (b * D_ + d) * (H_ * W4_) + w0q + c4;
            wp[(h0 + 3*grp + 0) * W4_] = make_ushort4(f2bf(a0.x), f2bf(a0.y), f2bf(a0.z), f2bf(a0.w));
            wp[(h0 + 3*grp + 1) * W4_] = make_ushort4(f2bf(a1.x), f2bf(a1.y), f2bf(a1.z), f2bf(a1.w));
            wp[(h0 + 3*grp + 2) * W4_] = make_ushort4(f2bf(a2.x), f2bf(a2.y), f2bf(a2.z), f2bf(a2.w));
        }
        __syncthreads();   // lds_in ready for next W-conv; wt consumed
    }
}

// ---------------- Kernel B: D-axis sliding window (bf16 -> f32) ------------
static __device__ inline float4 bf4_to_f4(ushort4 u) {
    return make_float4(__uint_as_float((unsigned)u.x << 16),
                       __uint_as_float((unsigned)u.y << 16),
                       __uint_as_float((unsigned)u.z << 16),
                       __uint_as_float((unsigned)u.w << 16));
}

template <int STR4, int LEN, int CH>
__global__ __launch_bounds__(256) void blur_d_slide(const ushort4* __restrict__ src,
                                                    float4* __restrict__ dst,
                                                    GaussW g, int ncol) {
    int tid = blockIdx.x * blockDim.x + threadIdx.x;
    int col = tid % ncol;
    int chunk = tid / ncol;
    int c0 = chunk * CH;
    int inner = col % STR4;
    int outer = col / STR4;
    int base = outer * (LEN * STR4) + inner;

    float4 ring[KSIZE];
#pragma unroll
    for (int j = 0; j < KSIZE - 1; ++j) {
        int cc = c0 - PAD + j;
        float4 v = make_float4(0.f, 0.f, 0.f, 0.f);
        if (cc >= 0 && cc < LEN) v = bf4_to_f4(src[base + cc * STR4]);
        ring[j] = v;
    }
#pragma unroll
    for (int k = 0; k < CH; ++k) {
        int cc = c0 + k + PAD;
        float4 v = make_float4(0.f, 0.f, 0.f, 0.f);
        if (cc < LEN) v = bf4_to_f4(src[base + cc * STR4]);
        ring[(KSIZE - 1 + k) % KSIZE] = v;

        float4 acc = make_float4(0.f, 0.f, 0.f, 0.f);
#pragma unroll
        for (int t = 0; t < KSIZE; ++t) {
            float4 u = ring[(k + t) % KSIZE];  // static after unroll
            float wt = g.w[t];
            acc.x += wt * u.x; acc.y += wt * u.y;
            acc.z += wt * u.z; acc.w += wt * u.w;
        }
        dst[base + (c0 + k) * STR4] = acc;
    }
}

// ---------------- Dense fallback (ws too small; never expected) ------------
__global__ void blur_dense_fallback(const float* __restrict__ src,
                                    float* __restrict__ dst,
                                    GaussW g, int B, int D, int H, int W) {
    long n = (long)B * D * H * W;
    long i = (long)blockIdx.x * blockDim.x + threadIdx.x;
    if (i >= n) return;
    int w = (int)(i % W);
    long r = i / W;
    int h = (int)(r % H); r /= H;
    int d = (int)(r % D);
    int b = (int)(r / D);

    float acc = 0.f;
    for (int td = 0; td < KSIZE; ++td) {
        int dd = d + td - PAD;
        if (dd < 0 || dd >= D) continue;
        for (int th = 0; th < KSIZE; ++th) {
            int hh = h + th - PAD;
            if (hh < 0 || hh >= H) continue;
            float wdh = g.w[td] * g.w[th];
            const float* row = src + (((long)b * D + dd) * H + hh) * W;
            for (int tw = 0; tw < KSIZE; ++tw) {
                int ww = w + tw - PAD;
                if (ww < 0 || ww >= W) continue;
                acc += wdh * g.w[tw] * row[ww];
            }
        }
    }
    dst[i] = acc;
}

extern "C" void kernel_launch(void* const* d_in, const int* in_sizes, int n_in,
                              void* d_out, int out_size, void* d_ws, size_t ws_size,
                              hipStream_t stream) {
    const float* x = (const float*)d_in[0];
    float* out = (float*)d_out;
    (void)in_sizes; (void)n_in; (void)out_size;

    const long n = (long)B_ * D_ * H_ * W_;   // 23,592,960

    GaussW g;
    {
        double tmp[KSIZE], s = 0.0;
        for (int i = 0; i < KSIZE; ++i) {
            double dd = (double)(i - PAD);
            tmp[i] = exp(-(dd * dd) / (2.0 * 1.5 * 1.5));
            s += tmp[i];
        }
        for (int i = 0; i < KSIZE; ++i) g.w[i] = (float)(tmp[i] / s);
    }

    if (ws_size >= (size_t)n * sizeof(unsigned short)) {
        // A: x (f32) -> ws (bf16), fused W+H per plane.
        blur_wh<<<NBLK_A, 256, 0, stream>>>((const float4*)x, (ushort4*)d_ws, g);
        // B: ws (bf16) -> out (f32), sliding window along D.
        const int ncol = B_ * H_ * W4_;           // 36864 (multiple of 256)
        const int threads = ncol * (D_ / 32);     // 184320
        blur_d_slide<9216, 160, 32><<<threads / 256, 256, 0, stream>>>(
            (const ushort4*)d_ws, (float4*)out, g, ncol);
    } else {
        long gridN = (n + 255) / 256;
        blur_dense_fallback<<<(int)gridN, 256, 0, stream>>>(x, out, g, B_, D_, H_, W_);
    }
}